// Round 13
// baseline (197.662 us; speedup 1.0000x reference)
//
#include <hip/hip_runtime.h>

// DynamicMaskHead fused kernel (v5: channel-streamed layer0 for occupancy):
//   x = concat(rel_coords(2), mask_feats[im_ind](8))  -> 10ch
//   h0 = relu(W0(8x10) x + b0); h1 = relu(W1(8x8) h0 + b1); logit = W2(1x8) h1 + b2
//   out = aligned_bilinear(logits, factor=2)
//
// History: v1 (LDS w, scalar reads) ~90-106us; v2 (+blocks) neutral; v3 (s_load w)
// 157us (VGPR=24, VALUBusy 89% @ occ 61% -> machine hides latency at 5 waves/SIMD);
// v4 (float4 w reads) ~82us @ VGPR~150 -> only 3 waves/SIMD, ~45% VALU issue eff.
// v5: layer0 goes CHANNEL-OUTER: load ch c for all 5 px, FMA into acc, never hold
// xf[5][8] (-40 VGPR). W0 staged TRANSPOSED in LDS so c-outer weight reads stay
// 2x float4 broadcasts. launch_bounds(256,4): 4 waves/SIMD, same work as v4.
// Logits tile lives in LDS; never hits HBM.

#define HH   128
#define WW   192
#define HW   (HH*WW)
#define OHH  256
#define OWW  384
#define THY  32          // output tile height
#define TWX  128         // output tile width
#define LR   18          // logits tile rows = THY/2 + 2
#define LC   66          // logits tile cols = TWX/2 + 2 (logical)
#define LCP  67          // padded row stride
#define NPX  (LR*LC)     // 1188
#define NPARAMS 169
#define PXT  5           // px per thread

__global__ __launch_bounds__(256, 4)
void dmh_fused(const float* __restrict__ mask_feats,
               const float* __restrict__ params,
               const float* __restrict__ locs,
               const int*   __restrict__ im_inds,
               const int*   __restrict__ fpn,
               float* __restrict__ out)
{
    // LDS weight layout:
    //  W0^T: [10 inputs][8 outputs]   [0..80)    (c-outer reads: 2x float4)
    //  W1  : 8 rows x 8               [80..144)  (o-outer reads: 2x float4)
    //  W2  : 8                        [144..152)
    //  b0  : 8 [152..160)  b1: 8 [160..168)  b2: 1 [168]
    __shared__ float sw[176];
    __shared__ float L[LR][LCP];

    const int inst = blockIdx.z;
    const int tid  = threadIdx.x;

    if (tid < NPARAMS) {
        const float v = params[(size_t)inst * NPARAMS + tid];
        int d;
        if      (tid <  80) d = (tid % 10) * 8 + (tid / 10);   // W0^T[c][o]
        else                d = tid;                           // W1,W2,biases keep offsets
        sw[d] = v;
    }

    const int   im     = im_inds[inst];
    const float instx  = locs[2*inst];
    const float insty  = locs[2*inst + 1];
    const float invsoi = 1.0f / (float)(64 << fpn[inst]);   // SOI = 64<<lvl (exact pow2)

    const int oy0 = blockIdx.y * THY;
    const int ox0 = blockIdx.x * TWX;
    const int r0  = oy0 >> 1;
    const int c0  = ox0 >> 1;

    __syncthreads();

    const float* __restrict__ fbase = mask_feats + (size_t)im * 8 * HW;

    // ---- phase 1a: per-px coords + base offsets (no feature array!) ----
    float rx[PXT], ry[PXT];
    int   foff[PXT];    // gy*WW+gx, 32-bit uniform-base offset
    int   pix[PXT];
#pragma unroll
    for (int k = 0; k < PXT; ++k) {
        int p = tid + 256*k;
        if (p > NPX-1) p = NPX-1;      // tail threads recompute last px (benign dup store)
        int lr = p / LC;
        int lc = p - lr*LC;
        pix[k] = lr*LCP + lc;
        int gy = r0 - 1 + lr; gy = gy < 0 ? 0 : (gy > HH-1 ? HH-1 : gy);
        int gx = c0 - 1 + lc; gx = gx < 0 ? 0 : (gx > WW-1 ? WW-1 : gx);
        rx[k] = (instx - (float)(gx*8 + 4)) * invsoi;
        ry[k] = (insty - (float)(gy*8 + 4)) * invsoi;
        foff[k] = gy*WW + gx;
    }

    // ---- layer 0: channel-outer streaming; acc[k][o], xf never materialized ----
    float h0[PXT][8];
    {
        // c=0: rx
        float4 A = *(const float4*)&sw[0];
        float4 B = *(const float4*)&sw[4];
#pragma unroll
        for (int k = 0; k < PXT; ++k) {
            h0[k][0] = A.x*rx[k]; h0[k][1] = A.y*rx[k];
            h0[k][2] = A.z*rx[k]; h0[k][3] = A.w*rx[k];
            h0[k][4] = B.x*rx[k]; h0[k][5] = B.y*rx[k];
            h0[k][6] = B.z*rx[k]; h0[k][7] = B.w*rx[k];
        }
        // c=1: ry
        A = *(const float4*)&sw[8];
        B = *(const float4*)&sw[12];
#pragma unroll
        for (int k = 0; k < PXT; ++k) {
            h0[k][0] += A.x*ry[k]; h0[k][1] += A.y*ry[k];
            h0[k][2] += A.z*ry[k]; h0[k][3] += A.w*ry[k];
            h0[k][4] += B.x*ry[k]; h0[k][5] += B.y*ry[k];
            h0[k][6] += B.z*ry[k]; h0[k][7] += B.w*ry[k];
        }
        // c=2..9: stream feature channels
#pragma unroll
        for (int cc = 0; cc < 8; ++cc) {
            const float* fp = fbase + cc*HW;
            float xv[PXT];
#pragma unroll
            for (int k = 0; k < PXT; ++k) xv[k] = fp[foff[k]];
            A = *(const float4*)&sw[(cc+2)*8];
            B = *(const float4*)&sw[(cc+2)*8 + 4];
#pragma unroll
            for (int k = 0; k < PXT; ++k) {
                h0[k][0] += A.x*xv[k]; h0[k][1] += A.y*xv[k];
                h0[k][2] += A.z*xv[k]; h0[k][3] += A.w*xv[k];
                h0[k][4] += B.x*xv[k]; h0[k][5] += B.y*xv[k];
                h0[k][6] += B.z*xv[k]; h0[k][7] += B.w*xv[k];
            }
        }
        // bias + relu
#pragma unroll
        for (int o = 0; o < 8; ++o) {
            const float b = sw[152 + o];
#pragma unroll
            for (int k = 0; k < PXT; ++k)
                h0[k][o] = fmaxf(h0[k][o] + b, 0.0f);
        }
    }

    // ---- layer 1: 8 <- 8, o-outer, relu ----
    float h1[PXT][8];
#pragma unroll
    for (int o = 0; o < 8; ++o) {
        const float4 A = *(const float4*)&sw[80 + 8*o];
        const float4 B = *(const float4*)&sw[80 + 8*o + 4];
        const float  b = sw[160 + o];
#pragma unroll
        for (int k = 0; k < PXT; ++k) {
            float a = A.x*h0[k][0] + A.y*h0[k][1] + A.z*h0[k][2] + A.w*h0[k][3]
                    + B.x*h0[k][4] + B.y*h0[k][5] + B.z*h0[k][6] + B.w*h0[k][7];
            h1[k][o] = fmaxf(a + b, 0.0f);
        }
    }

    // ---- layer 2: 1 <- 8, store logits tile ----
    {
        const float4 A = *(const float4*)&sw[144];
        const float4 B = *(const float4*)&sw[148];
        const float  b = sw[168];
#pragma unroll
        for (int k = 0; k < PXT; ++k) {
            float a = A.x*h1[k][0] + A.y*h1[k][1] + A.z*h1[k][2] + A.w*h1[k][3]
                    + B.x*h1[k][4] + B.y*h1[k][5] + B.z*h1[k][6] + B.w*h1[k][7];
            ((float*)L)[pix[k]] = a + b;
        }
    }

    __syncthreads();

    // ---- phase 2: aligned bilinear 2x, float4 stores ----
    float* __restrict__ obase = out + (size_t)inst * OHH * OWW;
#pragma unroll
    for (int j = 0; j < 4; ++j) {
        const int yl = (tid >> 5) + 8*j;
        const int xq = (tid & 31) * 4;
        const int y  = oy0 + yl;
        const int yy = (y > 0) ? (y - 1) : 0;
        const int iy0 = yy >> 1;
        const float fy = (yy & 1) ? 0.5f : 0.0f;
        const float gy1 = 1.0f - fy;
        const int ly = iy0 - r0 + 1;       // row iy0 lives at LDS row iy0-(r0-1)
        const int lx = xq >> 1;            // LDS col of global logits col m-1
        float t[3];
#pragma unroll
        for (int i = 0; i < 3; ++i) {
            const float a  = L[ly  ][lx + i];
            const float bb = L[ly+1][lx + i];
            t[i] = a*gy1 + bb*fy;          // rows first (matches reference axis order)
        }
        float4 r;
        r.x = 0.5f*t[0] + 0.5f*t[1];   // x even  : fx=0.5 between cols m-1,m
        r.y = t[1];                    // x odd   : fx=0, col m
        r.z = 0.5f*t[1] + 0.5f*t[2];   // x even  : cols m,m+1
        r.w = t[2];                    // x odd   : col m+1
        *(float4*)(obase + (size_t)y*OWW + ox0 + xq) = r;
    }
}

extern "C" void kernel_launch(void* const* d_in, const int* in_sizes, int n_in,
                              void* d_out, int out_size, void* d_ws, size_t ws_size,
                              hipStream_t stream) {
    const float* mask_feats = (const float*)d_in[0];
    const float* params     = (const float*)d_in[1];
    const float* locs       = (const float*)d_in[2];
    const int*   im_inds    = (const int*)d_in[3];
    const int*   fpn        = (const int*)d_in[4];
    float*       out        = (float*)d_out;

    const int n_inst = in_sizes[1] / NPARAMS;   // 400
    dim3 grid(OWW/TWX, OHH/THY, n_inst);        // (3, 8, 400)
    dmh_fused<<<grid, 256, 0, stream>>>(mask_feats, params, locs, im_inds, fpn, out);
}